// Round 2
// baseline (374.314 us; speedup 1.0000x reference)
//
#include <hip/hip_runtime.h>

// CoarseMatching on MI355X.
// Sizes: N=2, C=256, G0=G1=1600 (40x40), L0=L1=6400 (80x80), TOPK=8, K4=32.
// Outputs (flat f32, concat): h01 (2,6400,32) | h10 (2,32,6400) | scores (2,6400)
//   | j_best (2,6400, int-as-float) | mask (2,6400, 0/1) | x0_8x (2,256,80,80) | x1_8x.
// Workspace: sim + simT (40.96MB) + topk idx + h01p/h10p + score/jbest/ibest ~= 44.6MB.

#define N_B   2
#define C_DIM 256
#define G0N   1600
#define GW    40
#define L0N   6400
#define W_F   80
#define TK    8

// ---------------- K1: sim GEMM (A^T B, K=256) + transpose ----------------
// v2: 64x64 tile / 128 threads / 8x4 per thread / KC=32.
// Grid (25,25,2) = 1250 blocks x 2 waves = 2500 waves (2.44/SIMD) vs old 338 blocks
// (1.3/CU, VALUBusy 30%). 1600 = 25*64 exactly: no bounds guards anywhere.
// Accumulation order over k is unchanged (ascending 0..255) -> bitwise-same sim.
#define KC 32
__global__ __launch_bounds__(128) void k_sim(const float* __restrict__ p0,
                                             const float* __restrict__ p1,
                                             float* __restrict__ sim,
                                             float* __restrict__ simT) {
  const int n  = blockIdx.z;
  const int i0 = blockIdx.y * 64;
  const int j0 = blockIdx.x * 64;
  const float* A = p0 + (size_t)n * C_DIM * G0N;  // [c][i]
  const float* B = p1 + (size_t)n * C_DIM * G0N;  // [c][j]
  __shared__ float As[KC][64];
  __shared__ float Bs[KC][64];
  const int t  = threadIdx.x;
  const int tx = t & 15;   // 16 cols of 4  -> 64
  const int ty = t >> 4;   // 8 rows of 8   -> 64

  float4 acc[8];
#pragma unroll
  for (int ii = 0; ii < 8; ++ii) acc[ii] = make_float4(0.f, 0.f, 0.f, 0.f);

  for (int kc = 0; kc < C_DIM; kc += KC) {
    // stage 32x64 A-tile and B-tile: 512 float4 each, 4 per thread per tile
#pragma unroll
    for (int u = 0; u < 4; ++u) {
      int f   = t + u * 128;        // 0..511
      int row = f >> 4;             // 16 float4 per row
      int c4  = (f & 15) * 4;
      *(float4*)&As[row][c4] = *(const float4*)(A + (size_t)(kc + row) * G0N + i0 + c4);
      *(float4*)&Bs[row][c4] = *(const float4*)(B + (size_t)(kc + row) * G0N + j0 + c4);
    }
    __syncthreads();
#pragma unroll
    for (int k = 0; k < KC; ++k) {
      __attribute__((aligned(16))) float a[8];
      *(float4*)&a[0] = *(const float4*)&As[k][ty * 8];
      *(float4*)&a[4] = *(const float4*)&As[k][ty * 8 + 4];
      float4 bv = *(const float4*)&Bs[k][tx * 4];
#pragma unroll
      for (int ii = 0; ii < 8; ++ii) {
        acc[ii].x += a[ii] * bv.x;
        acc[ii].y += a[ii] * bv.y;
        acc[ii].z += a[ii] * bv.z;
        acc[ii].w += a[ii] * bv.w;
      }
    }
    __syncthreads();
  }

  float* simn  = sim  + (size_t)n * G0N * G0N;
  float* simTn = simT + (size_t)n * G0N * G0N;
  const int ib = i0 + ty * 8;
  const int jb = j0 + tx * 4;
  const float* accf = (const float*)acc;  // [ii*4 + jj]
#pragma unroll
  for (int ii = 0; ii < 8; ++ii)
    *(float4*)(simn + (size_t)(ib + ii) * G0N + jb) = acc[ii];
#pragma unroll
  for (int jj = 0; jj < 4; ++jj) {
    float4 lo = make_float4(accf[0 * 4 + jj], accf[1 * 4 + jj], accf[2 * 4 + jj], accf[3 * 4 + jj]);
    float4 hi = make_float4(accf[4 * 4 + jj], accf[5 * 4 + jj], accf[6 * 4 + jj], accf[7 * 4 + jj]);
    *(float4*)(simTn + (size_t)(jb + jj) * G0N + ib)     = lo;
    *(float4*)(simTn + (size_t)(jb + jj) * G0N + ib + 4) = hi;
  }
}

// ---------------- K2: top-8 per row (one wave / row), JAX tie-break ----------------
__global__ __launch_bounds__(256) void k_topk(const float* __restrict__ sim,
                                              const float* __restrict__ simT,
                                              int* __restrict__ i01,
                                              int* __restrict__ i10) {
  int wid  = (blockIdx.x * 256 + threadIdx.x) >> 6;  // 0..6399
  int lane = threadIdx.x & 63;
  int dir  = wid / (N_B * G0N);
  int r    = wid - dir * (N_B * G0N);
  const float* row = (dir ? simT : sim) + (size_t)r * G0N;
  int* out = (dir ? i10 : i01) + r * TK;

  float v[25];
#pragma unroll
  for (int tt = 0; tt < 25; ++tt) v[tt] = row[lane + 64 * tt];

#pragma unroll 1
  for (int k = 0; k < TK; ++k) {
    float best = -3.4e38f; int bidx = 0x7fffffff;
#pragma unroll
    for (int tt = 0; tt < 25; ++tt) {
      if (v[tt] > best) { best = v[tt]; bidx = lane + 64 * tt; }
    }
#pragma unroll
    for (int off = 1; off < 64; off <<= 1) {
      float ov = __shfl_xor(best, off);
      int   oi = __shfl_xor(bidx, off);
      if (ov > best || (ov == best && oi < bidx)) { best = ov; bidx = oi; }
    }
    if (lane == 0) out[k] = bidx;
#pragma unroll
    for (int tt = 0; tt < 25; ++tt)
      if (lane + 64 * tt == bidx) v[tt] = -3.4e38f;
  }
}

// ---------------- K3: pre-softmax heatmaps, v2: one wave per (n,g), no LDS ----------------
// Old: 36.5KB LDS/block -> 4 blocks/CU -> 8 waves/CU, Occupancy 18%, 1.4 TB/s.
// New: zero LDS. Wave lane = (k4 in [0,32), cs in {0,1}); each lane streams att row k4,
// c-half cs as 32 sequential float4 (one 128B line per thread via L1, full-line use).
// x reads are lane-uniform per 32-half (2 addresses/instr, broadcast-coalesced).
// Halves combined with one shfl_xor(32); softmax xor-ladder identical to v1.
// wid in [0,6400): [0,3200) -> (x0,a01,h01p); [3200,6400) -> (x1,a10,h10p)
__global__ __launch_bounds__(256) void k_heat(const float* __restrict__ x0,
                                              const float* __restrict__ a01,
                                              float* __restrict__ h01p,
                                              const float* __restrict__ x1,
                                              const float* __restrict__ a10,
                                              float* __restrict__ h10p) {
  int wid  = blockIdx.x * 4 + (threadIdx.x >> 6);
  int lane = threadIdx.x & 63;
  int k4   = lane & 31;
  int cs   = lane >> 5;
  const float* x   = x0;
  const float* att = a01;
  float*      hpre = h01p;
  int ng = wid;
  if (wid >= N_B * G0N) { x = x1; att = a10; hpre = h10p; ng = wid - N_B * G0N; }
  const float* ar = att + ((size_t)ng * 32 + k4) * C_DIM + cs * 128;
  const float* xr = x   + (size_t)ng * 4 * C_DIM + cs * 128;

  float acc0 = 0.f, acc1 = 0.f, acc2 = 0.f, acc3 = 0.f;
#pragma unroll 8
  for (int it = 0; it < 32; ++it) {
    float4 av  = *(const float4*)(ar + it * 4);
    float4 xv0 = *(const float4*)(xr + 0 * C_DIM + it * 4);
    float4 xv1 = *(const float4*)(xr + 1 * C_DIM + it * 4);
    float4 xv2 = *(const float4*)(xr + 2 * C_DIM + it * 4);
    float4 xv3 = *(const float4*)(xr + 3 * C_DIM + it * 4);
    acc0 += av.x * xv0.x + av.y * xv0.y + av.z * xv0.z + av.w * xv0.w;
    acc1 += av.x * xv1.x + av.y * xv1.y + av.z * xv1.z + av.w * xv1.w;
    acc2 += av.x * xv2.x + av.y * xv2.y + av.z * xv2.z + av.w * xv2.w;
    acc3 += av.x * xv3.x + av.y * xv3.y + av.z * xv3.z + av.w * xv3.w;
  }
  // combine c-halves: lane k4 and lane k4+32 hold the two partials
  acc0 += __shfl_xor(acc0, 32);
  acc1 += __shfl_xor(acc1, 32);
  acc2 += __shfl_xor(acc2, 32);
  acc3 += __shfl_xor(acc3, 32);

  float l0 = (acc0 * (1.0f / 256.0f)) / 0.1f;  // /C then /TEMP, reference order
  float l1 = (acc1 * (1.0f / 256.0f)) / 0.1f;
  float l2 = (acc2 * (1.0f / 256.0f)) / 0.1f;
  float l3 = (acc3 * (1.0f / 256.0f)) / 0.1f;

  float m0 = l0, m1 = l1, m2 = l2, m3 = l3;
#pragma unroll
  for (int off = 1; off < 32; off <<= 1) {
    m0 = fmaxf(m0, __shfl_xor(m0, off));
    m1 = fmaxf(m1, __shfl_xor(m1, off));
    m2 = fmaxf(m2, __shfl_xor(m2, off));
    m3 = fmaxf(m3, __shfl_xor(m3, off));
  }
  float e0 = expf(l0 - m0), e1 = expf(l1 - m1), e2 = expf(l2 - m2), e3 = expf(l3 - m3);
  float s0 = e0, s1 = e1, s2 = e2, s3 = e3;
#pragma unroll
  for (int off = 1; off < 32; off <<= 1) {
    s0 += __shfl_xor(s0, off);
    s1 += __shfl_xor(s1, off);
    s2 += __shfl_xor(s2, off);
    s3 += __shfl_xor(s3, off);
  }
  float* op = hpre + (size_t)ng * 128 + k4;
  if (cs == 0) {
    op[0]  = e0 / s0;   // q=0: lanes 0..31 -> contiguous 128B
    op[32] = e1 / s1;   // q=1
  } else {
    op[64] = e2 / s2;   // q=2
    op[96] = e3 / s3;   // q=3
  }
}

// ---------------- K4a: fused h01 + row argmax(first) -> score, j_best ----------------
__global__ __launch_bounds__(256) void k_fuse01(const float* __restrict__ h01p,
                                                const float* __restrict__ h10p,
                                                const int* __restrict__ i01,
                                                const int* __restrict__ i10,
                                                float* __restrict__ h01_out,
                                                float* __restrict__ score_ws,
                                                int* __restrict__ jbest_ws,
                                                float* __restrict__ jbest_out) {
  int idx = blockIdx.x * 8 + (threadIdx.x >> 5);  // (n,l0)
  int k4  = threadIdx.x & 31;
  int n = idx / L0N, l0 = idx - n * L0N;
  int r0 = l0 / W_F, c0 = l0 - r0 * W_F;
  int g0 = (r0 >> 1) * GW + (c0 >> 1);
  int q0 = ((r0 & 1) << 1) | (c0 & 1);
  int k = k4 >> 2, g = k4 & 3;
  int jc = i01[(n * G0N + g0) * TK + k];
  // mutual check: exists k' with i10[n][jc][k'] == g0, grid offset must equal q0; q1(j)=g
  const int* row10 = i10 + (n * G0N + jc) * TK;
  int kf = -1;
#pragma unroll
  for (int kp = 0; kp < 8; ++kp) if (row10[kp] == g0) kf = kp;
  float m = 0.f;
  if (kf >= 0) m = h10p[((n * G0N + jc) * 4 + g) * 32 + kf * 4 + q0];
  float h = h01p[((n * G0N + g0) * 4 + q0) * 32 + k4];
  float val = h * m;
  h01_out[(size_t)idx * 32 + k4] = val;

  float best = val; int bi = k4;  // first-argmax: min index on ties
#pragma unroll
  for (int off = 1; off < 32; off <<= 1) {
    float ov = __shfl_xor(best, off);
    int   oi = __shfl_xor(bi, off);
    if (ov > best || (ov == best && oi < bi)) { best = ov; bi = oi; }
  }
  if (k4 == 0) {
    score_ws[idx] = best;
    int kB = bi >> 2, gB = bi & 3;
    int jcB = i01[(n * G0N + g0) * TK + kB];
    int jrow = jcB / GW;
    int jb = ((jrow * 2 + (gB >> 1)) * W_F) + (jcB - jrow * GW) * 2 + (gB & 1);
    if (r0 < 2 || r0 >= W_F - 2 || c0 < 2 || c0 >= W_F - 2) jb = 0;  // border on position
    jbest_ws[idx]  = jb;
    jbest_out[idx] = (float)jb;
  }
}

// ---------------- K4b: fused h10 + col argmax(first) -> i_best ----------------
__global__ __launch_bounds__(256) void k_fuse10(const float* __restrict__ h01p,
                                                const float* __restrict__ h10p,
                                                const int* __restrict__ i01,
                                                const int* __restrict__ i10,
                                                float* __restrict__ h10_out,
                                                int* __restrict__ ibest_ws) {
  int idx = blockIdx.x * 8 + (threadIdx.x >> 5);  // (n,l1)
  int k4  = threadIdx.x & 31;
  int n = idx / L0N, l1 = idx - n * L0N;
  int r1 = l1 / W_F, c1 = l1 - r1 * W_F;
  int g1 = (r1 >> 1) * GW + (c1 >> 1);
  int q1 = ((r1 & 1) << 1) | (c1 & 1);
  int k = k4 >> 2, g = k4 & 3;
  int ic = i10[(n * G0N + g1) * TK + k];
  const int* row01 = i01 + (n * G0N + ic) * TK;
  int kf = -1;
#pragma unroll
  for (int kp = 0; kp < 8; ++kp) if (row01[kp] == g1) kf = kp;
  float m = 0.f;
  if (kf >= 0) m = h01p[((n * G0N + ic) * 4 + g) * 32 + kf * 4 + q1];
  float h = h10p[((n * G0N + g1) * 4 + q1) * 32 + k4];
  float val = h * m;
  h10_out[((size_t)n * 32 + k4) * L0N + l1] = val;

  float best = val; int bi = k4;
#pragma unroll
  for (int off = 1; off < 32; off <<= 1) {
    float ov = __shfl_xor(best, off);
    int   oi = __shfl_xor(bi, off);
    if (ov > best || (ov == best && oi < bi)) { best = ov; bi = oi; }
  }
  if (k4 == 0) {
    int kB = bi >> 2, gB = bi & 3;
    int icB = i10[(n * G0N + g1) * TK + kB];
    int irow = icB / GW;
    int ib = ((irow * 2 + (gB >> 1)) * W_F) + (icB - irow * GW) * 2 + (gB & 1);
    if (r1 < 2 || r1 >= W_F - 2 || c1 < 2 || c1 >= W_F - 2) ib = 0;
    ibest_ws[idx] = ib;
  }
}

// ---------------- K5: bi-projection mask + masked scores ----------------
__global__ __launch_bounds__(256) void k_final(const float* __restrict__ score_ws,
                                               const int* __restrict__ jbest_ws,
                                               const int* __restrict__ ibest_ws,
                                               float* __restrict__ scores_out,
                                               float* __restrict__ mask_out) {
  int idx = blockIdx.x * 256 + threadIdx.x;
  if (idx >= N_B * L0N) return;
  int n = idx / L0N, l0 = idx - n * L0N;
  int jb = jbest_ws[idx];
  float sc = score_ws[idx];
  int biproj = ibest_ws[n * L0N + jb];
  bool mk = (biproj == l0) && (l0 != 0) && (sc > 0.2f);
  scores_out[idx] = mk ? sc : 0.f;
  mask_out[idx]   = mk ? 1.f : 0.f;
}

// ---------------- K6: unpatchify via 32x32 LDS transpose tiles ----------------
// merged: blockIdx.z in [0,16) -> (x0 -> out0); [16,32) -> (x1 -> out1)
__global__ __launch_bounds__(256) void k_unpatch(const float* __restrict__ x0,
                                                 float* __restrict__ out0,
                                                 const float* __restrict__ x1,
                                                 float* __restrict__ out1) {
  __shared__ float tile[32][33];
  int z = blockIdx.z;
  const float* x = (z < 16) ? x0 : x1;
  float* out     = (z < 16) ? out0 : out1;
  int zz  = z & 15;
  int cc0 = blockIdx.x * 32;
  int r   = blockIdx.y;
  int n   = zz >> 3;
  int c0  = (zz & 7) * 32;
  int t = threadIdx.x;
  int sr = r & 1, ghr = r >> 1;
  int pos = t >> 5, cl = t & 31;
#pragma unroll
  for (int it = 0; it < 4; ++it) {
    int p = pos + it * 8;
    int cc = cc0 + p;
    if (cc < W_F) {
      int gg = ghr * GW + (cc >> 1);
      int qq = (sr << 1) | (cc & 1);
      tile[p][cl] = x[(((size_t)n * G0N + gg) * 4 + qq) * C_DIM + c0 + cl];
    }
  }
  __syncthreads();
  int co = t >> 5, p2 = t & 31;
#pragma unroll
  for (int it = 0; it < 4; ++it) {
    int c = c0 + co + it * 8;
    int cc = cc0 + p2;
    if (cc < W_F)
      out[(((size_t)n * C_DIM + c) * W_F + r) * W_F + cc] = tile[p2][co + it * 8];
  }
}

extern "C" void kernel_launch(void* const* d_in, const int* in_sizes, int n_in,
                              void* d_out, int out_size, void* d_ws, size_t ws_size,
                              hipStream_t stream) {
  const float* x0  = (const float*)d_in[0];
  const float* x1  = (const float*)d_in[1];
  const float* a01 = (const float*)d_in[2];
  const float* a10 = (const float*)d_in[3];
  const float* p0  = (const float*)d_in[4];
  const float* p1  = (const float*)d_in[5];
  float* out = (float*)d_out;

  float* ws       = (float*)d_ws;
  float* sim      = ws;                      // 2*1600*1600
  float* simT     = ws + 5120000;            // 2*1600*1600
  int*   i01      = (int*)(ws + 10240000);   // 2*1600*8
  int*   i10      = (int*)(ws + 10265600);
  float* h01p     = ws + 10291200;           // 2*1600*4*32
  float* h10p     = ws + 10700800;
  float* score_ws = ws + 11110400;           // 2*6400
  int*   jbest_ws = (int*)(ws + 11123200);
  int*   ibest_ws = (int*)(ws + 11136000);   // end: 11,148,800 floats (~44.6MB)

  float* o_h01   = out;
  float* o_h10   = out + 409600;
  float* o_score = out + 819200;
  float* o_jbest = out + 832000;
  float* o_mask  = out + 844800;
  float* o_x08   = out + 857600;
  float* o_x18   = out + 4134400;

  k_sim<<<dim3(25, 25, 2), 128, 0, stream>>>(p0, p1, sim, simT);
  k_topk<<<1600, 256, 0, stream>>>(sim, simT, i01, i10);
  k_heat<<<1600, 256, 0, stream>>>(x0, a01, h01p, x1, a10, h10p);
  k_fuse01<<<1600, 256, 0, stream>>>(h01p, h10p, i01, i10, o_h01, score_ws, jbest_ws, o_jbest);
  k_fuse10<<<1600, 256, 0, stream>>>(h01p, h10p, i01, i10, o_h10, ibest_ws);
  k_final<<<50, 256, 0, stream>>>(score_ws, jbest_ws, ibest_ws, o_score, o_mask);
  k_unpatch<<<dim3(3, 80, 32), 256, 0, stream>>>(x0, o_x08, x1, o_x18);
}

// Round 3
// 338.498 us; speedup vs baseline: 1.1058x; 1.1058x over previous
//
#include <hip/hip_runtime.h>

// CoarseMatching on MI355X.
// Sizes: N=2, C=256, G0=G1=1600 (40x40), L0=L1=6400 (80x80), TOPK=8, K4=32.
// Outputs (flat f32, concat): h01 (2,6400,32) | h10 (2,32,6400) | scores (2,6400)
//   | j_best (2,6400, int-as-float) | mask (2,6400, 0/1) | x0_8x (2,256,80,80) | x1_8x.
// Workspace: sim + simT (40.96MB) + topk idx + h01p/h10p + score/jbest/ibest ~= 44.6MB.

#define N_B   2
#define C_DIM 256
#define G0N   1600
#define GW    40
#define L0N   6400
#define W_F   80
#define TK    8

// ---------------- K1: sim GEMM (A^T B, K=256) + transpose ----------------
// v2: 64x64 tile / 128 threads / 8x4 per thread / KC=32. Grid (25,25,2)=1250 blocks.
#define KC 32
__global__ __launch_bounds__(128) void k_sim(const float* __restrict__ p0,
                                             const float* __restrict__ p1,
                                             float* __restrict__ sim,
                                             float* __restrict__ simT) {
  const int n  = blockIdx.z;
  const int i0 = blockIdx.y * 64;
  const int j0 = blockIdx.x * 64;
  const float* A = p0 + (size_t)n * C_DIM * G0N;  // [c][i]
  const float* B = p1 + (size_t)n * C_DIM * G0N;  // [c][j]
  __shared__ float As[KC][64];
  __shared__ float Bs[KC][64];
  const int t  = threadIdx.x;
  const int tx = t & 15;   // 16 cols of 4  -> 64
  const int ty = t >> 4;   // 8 rows of 8   -> 64

  float4 acc[8];
#pragma unroll
  for (int ii = 0; ii < 8; ++ii) acc[ii] = make_float4(0.f, 0.f, 0.f, 0.f);

  for (int kc = 0; kc < C_DIM; kc += KC) {
    // stage 32x64 A-tile and B-tile: 512 float4 each, 4 per thread per tile
#pragma unroll
    for (int u = 0; u < 4; ++u) {
      int f   = t + u * 128;        // 0..511
      int row = f >> 4;             // 16 float4 per row
      int c4  = (f & 15) * 4;
      *(float4*)&As[row][c4] = *(const float4*)(A + (size_t)(kc + row) * G0N + i0 + c4);
      *(float4*)&Bs[row][c4] = *(const float4*)(B + (size_t)(kc + row) * G0N + j0 + c4);
    }
    __syncthreads();
#pragma unroll
    for (int k = 0; k < KC; ++k) {
      __attribute__((aligned(16))) float a[8];
      *(float4*)&a[0] = *(const float4*)&As[k][ty * 8];
      *(float4*)&a[4] = *(const float4*)&As[k][ty * 8 + 4];
      float4 bv = *(const float4*)&Bs[k][tx * 4];
#pragma unroll
      for (int ii = 0; ii < 8; ++ii) {
        acc[ii].x += a[ii] * bv.x;
        acc[ii].y += a[ii] * bv.y;
        acc[ii].z += a[ii] * bv.z;
        acc[ii].w += a[ii] * bv.w;
      }
    }
    __syncthreads();
  }

  float* simn  = sim  + (size_t)n * G0N * G0N;
  float* simTn = simT + (size_t)n * G0N * G0N;
  const int ib = i0 + ty * 8;
  const int jb = j0 + tx * 4;
  const float* accf = (const float*)acc;  // [ii*4 + jj]
#pragma unroll
  for (int ii = 0; ii < 8; ++ii)
    *(float4*)(simn + (size_t)(ib + ii) * G0N + jb) = acc[ii];
#pragma unroll
  for (int jj = 0; jj < 4; ++jj) {
    float4 lo = make_float4(accf[0 * 4 + jj], accf[1 * 4 + jj], accf[2 * 4 + jj], accf[3 * 4 + jj]);
    float4 hi = make_float4(accf[4 * 4 + jj], accf[5 * 4 + jj], accf[6 * 4 + jj], accf[7 * 4 + jj]);
    *(float4*)(simTn + (size_t)(jb + jj) * G0N + ib)     = lo;
    *(float4*)(simTn + (size_t)(jb + jj) * G0N + ib + 4) = hi;
  }
}

// ---------------- K2: top-8 per row (one wave / row), JAX tie-break ----------------
__global__ __launch_bounds__(256) void k_topk(const float* __restrict__ sim,
                                              const float* __restrict__ simT,
                                              int* __restrict__ i01,
                                              int* __restrict__ i10) {
  int wid  = (blockIdx.x * 256 + threadIdx.x) >> 6;  // 0..6399
  int lane = threadIdx.x & 63;
  int dir  = wid / (N_B * G0N);
  int r    = wid - dir * (N_B * G0N);
  const float* row = (dir ? simT : sim) + (size_t)r * G0N;
  int* out = (dir ? i10 : i01) + r * TK;

  float v[25];
#pragma unroll
  for (int tt = 0; tt < 25; ++tt) v[tt] = row[lane + 64 * tt];

#pragma unroll 1
  for (int k = 0; k < TK; ++k) {
    float best = -3.4e38f; int bidx = 0x7fffffff;
#pragma unroll
    for (int tt = 0; tt < 25; ++tt) {
      if (v[tt] > best) { best = v[tt]; bidx = lane + 64 * tt; }
    }
#pragma unroll
    for (int off = 1; off < 64; off <<= 1) {
      float ov = __shfl_xor(best, off);
      int   oi = __shfl_xor(bidx, off);
      if (ov > best || (ov == best && oi < bidx)) { best = ov; bidx = oi; }
    }
    if (lane == 0) out[k] = bidx;
#pragma unroll
    for (int tt = 0; tt < 25; ++tt)
      if (lane + 64 * tt == bidx) v[tt] = -3.4e38f;
  }
}

// ---------------- K3: pre-softmax heatmaps, v3: coalesced, near-zero LDS ----------------
// v1 (LDS-staged, coalesced): 86us, 36.5KB LDS -> 4 blocks/CU, Occ 18%.
// v2 (no-LDS, per-lane stream): 115us -- each wave load touched 64 lines (1KB lane
//     stride), 8x line-requests/instr, FETCH +48MB. REVERTED.
// v3: thread t = (row=t>>3, sub=t&7). att load: 8 rows x 128B contiguous = 8 lines
//     per wave instr (ideal). x load: 8 sub-addrs span one 128B line (broadcast).
//     3-shuffle sub-reduce -> 528B LDS -> same 32-lane softmax ladder as v1.
// One block per (n,g): [0,3200)->(x0,a01,h01p); [3200,6400)->(x1,a10,h10p).
__global__ __launch_bounds__(256) void k_heat(const float* __restrict__ x0,
                                              const float* __restrict__ a01,
                                              float* __restrict__ h01p,
                                              const float* __restrict__ x1,
                                              const float* __restrict__ a10,
                                              float* __restrict__ h10p) {
  int bid = blockIdx.x;   // 0..6399
  const float* x   = x0;
  const float* att = a01;
  float*      hpre = h01p;
  int ng = bid;
  if (bid >= N_B * G0N) { x = x1; att = a10; hpre = h10p; ng = bid - N_B * G0N; }
  const int t   = threadIdx.x;
  const int row = t >> 3;   // att row k4: 0..31
  const int sub = t & 7;    // c-chunk: 0..7
  const float* ar = att + ((size_t)ng * 32 + row) * C_DIM + sub * 4;
  const float* xr = x   + (size_t)ng * 4 * C_DIM + sub * 4;

  float a0 = 0.f, a1 = 0.f, a2 = 0.f, a3 = 0.f;
#pragma unroll
  for (int it = 0; it < 8; ++it) {
    float4 av  = *(const float4*)(ar + it * 32);
    float4 xv0 = *(const float4*)(xr + 0 * C_DIM + it * 32);
    float4 xv1 = *(const float4*)(xr + 1 * C_DIM + it * 32);
    float4 xv2 = *(const float4*)(xr + 2 * C_DIM + it * 32);
    float4 xv3 = *(const float4*)(xr + 3 * C_DIM + it * 32);
    a0 += av.x * xv0.x + av.y * xv0.y + av.z * xv0.z + av.w * xv0.w;
    a1 += av.x * xv1.x + av.y * xv1.y + av.z * xv1.z + av.w * xv1.w;
    a2 += av.x * xv2.x + av.y * xv2.y + av.z * xv2.z + av.w * xv2.w;
    a3 += av.x * xv3.x + av.y * xv3.y + av.z * xv3.z + av.w * xv3.w;
  }
  // reduce the 8 c-chunks (lanes row*8+sub, sub=0..7): xor 1,2,4
#pragma unroll
  for (int off = 1; off < 8; off <<= 1) {
    a0 += __shfl_xor(a0, off);
    a1 += __shfl_xor(a1, off);
    a2 += __shfl_xor(a2, off);
    a3 += __shfl_xor(a3, off);
  }
  __shared__ float dots[4][33];  // [q][k4], padded col -> conflict-free
  if (sub == 0) {
    dots[0][row] = a0;
    dots[1][row] = a1;
    dots[2][row] = a2;
    dots[3][row] = a3;
  }
  __syncthreads();
  if (t < 128) {
    int q = t >> 5, k4 = t & 31;
    float l = (dots[q][k4] * (1.0f / 256.0f)) / 0.1f;  // /C then /TEMP, reference order
    float m = l;
#pragma unroll
    for (int off = 1; off < 32; off <<= 1) m = fmaxf(m, __shfl_xor(m, off));
    float e = expf(l - m);
    float s = e;
#pragma unroll
    for (int off = 1; off < 32; off <<= 1) s += __shfl_xor(s, off);
    hpre[(size_t)ng * 128 + q * 32 + k4] = e / s;
  }
}

// ---------------- K4: fused mutual-mask + argmax (merged 01|10 halves) ----------------
// blocks [0,1600): h01 path (score/jbest); [1600,3200): h10 path (ibest).
__global__ __launch_bounds__(256) void k_fuse(const float* __restrict__ h01p,
                                              const float* __restrict__ h10p,
                                              const int* __restrict__ i01,
                                              const int* __restrict__ i10,
                                              float* __restrict__ h01_out,
                                              float* __restrict__ h10_out,
                                              float* __restrict__ score_ws,
                                              int* __restrict__ jbest_ws,
                                              float* __restrict__ jbest_out,
                                              int* __restrict__ ibest_ws) {
  if (blockIdx.x < 1600) {
    int idx = blockIdx.x * 8 + (threadIdx.x >> 5);  // (n,l0)
    int k4  = threadIdx.x & 31;
    int n = idx / L0N, l0 = idx - n * L0N;
    int r0 = l0 / W_F, c0 = l0 - r0 * W_F;
    int g0 = (r0 >> 1) * GW + (c0 >> 1);
    int q0 = ((r0 & 1) << 1) | (c0 & 1);
    int k = k4 >> 2, g = k4 & 3;
    int jc = i01[(n * G0N + g0) * TK + k];
    // mutual check: exists k' with i10[n][jc][k'] == g0; q1(j)=g
    const int* row10 = i10 + (n * G0N + jc) * TK;
    int kf = -1;
#pragma unroll
    for (int kp = 0; kp < 8; ++kp) if (row10[kp] == g0) kf = kp;
    float m = 0.f;
    if (kf >= 0) m = h10p[((n * G0N + jc) * 4 + g) * 32 + kf * 4 + q0];
    float h = h01p[((n * G0N + g0) * 4 + q0) * 32 + k4];
    float val = h * m;
    h01_out[(size_t)idx * 32 + k4] = val;

    float best = val; int bi = k4;  // first-argmax: min index on ties
#pragma unroll
    for (int off = 1; off < 32; off <<= 1) {
      float ov = __shfl_xor(best, off);
      int   oi = __shfl_xor(bi, off);
      if (ov > best || (ov == best && oi < bi)) { best = ov; bi = oi; }
    }
    if (k4 == 0) {
      score_ws[idx] = best;
      int kB = bi >> 2, gB = bi & 3;
      int jcB = i01[(n * G0N + g0) * TK + kB];
      int jrow = jcB / GW;
      int jb = ((jrow * 2 + (gB >> 1)) * W_F) + (jcB - jrow * GW) * 2 + (gB & 1);
      if (r0 < 2 || r0 >= W_F - 2 || c0 < 2 || c0 >= W_F - 2) jb = 0;  // border on position
      jbest_ws[idx]  = jb;
      jbest_out[idx] = (float)jb;
    }
  } else {
    int idx = (blockIdx.x - 1600) * 8 + (threadIdx.x >> 5);  // (n,l1)
    int k4  = threadIdx.x & 31;
    int n = idx / L0N, l1 = idx - n * L0N;
    int r1 = l1 / W_F, c1 = l1 - r1 * W_F;
    int g1 = (r1 >> 1) * GW + (c1 >> 1);
    int q1 = ((r1 & 1) << 1) | (c1 & 1);
    int k = k4 >> 2, g = k4 & 3;
    int ic = i10[(n * G0N + g1) * TK + k];
    const int* row01 = i01 + (n * G0N + ic) * TK;
    int kf = -1;
#pragma unroll
    for (int kp = 0; kp < 8; ++kp) if (row01[kp] == g1) kf = kp;
    float m = 0.f;
    if (kf >= 0) m = h01p[((n * G0N + ic) * 4 + g) * 32 + kf * 4 + q1];
    float h = h10p[((n * G0N + g1) * 4 + q1) * 32 + k4];
    float val = h * m;
    h10_out[((size_t)n * 32 + k4) * L0N + l1] = val;

    float best = val; int bi = k4;
#pragma unroll
    for (int off = 1; off < 32; off <<= 1) {
      float ov = __shfl_xor(best, off);
      int   oi = __shfl_xor(bi, off);
      if (ov > best || (ov == best && oi < bi)) { best = ov; bi = oi; }
    }
    if (k4 == 0) {
      int kB = bi >> 2, gB = bi & 3;
      int icB = i10[(n * G0N + g1) * TK + kB];
      int irow = icB / GW;
      int ib = ((irow * 2 + (gB >> 1)) * W_F) + (icB - irow * GW) * 2 + (gB & 1);
      if (r1 < 2 || r1 >= W_F - 2 || c1 < 2 || c1 >= W_F - 2) ib = 0;
      ibest_ws[idx] = ib;
    }
  }
}

// ---------------- K5: bi-projection mask + masked scores ----------------
__global__ __launch_bounds__(256) void k_final(const float* __restrict__ score_ws,
                                               const int* __restrict__ jbest_ws,
                                               const int* __restrict__ ibest_ws,
                                               float* __restrict__ scores_out,
                                               float* __restrict__ mask_out) {
  int idx = blockIdx.x * 256 + threadIdx.x;
  if (idx >= N_B * L0N) return;
  int n = idx / L0N, l0 = idx - n * L0N;
  int jb = jbest_ws[idx];
  float sc = score_ws[idx];
  int biproj = ibest_ws[n * L0N + jb];
  bool mk = (biproj == l0) && (l0 != 0) && (sc > 0.2f);
  scores_out[idx] = mk ? sc : 0.f;
  mask_out[idx]   = mk ? 1.f : 0.f;
}

// ---------------- K6: unpatchify via 32x32 LDS transpose tiles ----------------
// merged: blockIdx.z in [0,16) -> (x0 -> out0); [16,32) -> (x1 -> out1)
__global__ __launch_bounds__(256) void k_unpatch(const float* __restrict__ x0,
                                                 float* __restrict__ out0,
                                                 const float* __restrict__ x1,
                                                 float* __restrict__ out1) {
  __shared__ float tile[32][33];
  int z = blockIdx.z;
  const float* x = (z < 16) ? x0 : x1;
  float* out     = (z < 16) ? out0 : out1;
  int zz  = z & 15;
  int cc0 = blockIdx.x * 32;
  int r   = blockIdx.y;
  int n   = zz >> 3;
  int c0  = (zz & 7) * 32;
  int t = threadIdx.x;
  int sr = r & 1, ghr = r >> 1;
  int pos = t >> 5, cl = t & 31;
#pragma unroll
  for (int it = 0; it < 4; ++it) {
    int p = pos + it * 8;
    int cc = cc0 + p;
    if (cc < W_F) {
      int gg = ghr * GW + (cc >> 1);
      int qq = (sr << 1) | (cc & 1);
      tile[p][cl] = x[(((size_t)n * G0N + gg) * 4 + qq) * C_DIM + c0 + cl];
    }
  }
  __syncthreads();
  int co = t >> 5, p2 = t & 31;
#pragma unroll
  for (int it = 0; it < 4; ++it) {
    int c = c0 + co + it * 8;
    int cc = cc0 + p2;
    if (cc < W_F)
      out[(((size_t)n * C_DIM + c) * W_F + r) * W_F + cc] = tile[p2][co + it * 8];
  }
}

extern "C" void kernel_launch(void* const* d_in, const int* in_sizes, int n_in,
                              void* d_out, int out_size, void* d_ws, size_t ws_size,
                              hipStream_t stream) {
  const float* x0  = (const float*)d_in[0];
  const float* x1  = (const float*)d_in[1];
  const float* a01 = (const float*)d_in[2];
  const float* a10 = (const float*)d_in[3];
  const float* p0  = (const float*)d_in[4];
  const float* p1  = (const float*)d_in[5];
  float* out = (float*)d_out;

  float* ws       = (float*)d_ws;
  float* sim      = ws;                      // 2*1600*1600
  float* simT     = ws + 5120000;            // 2*1600*1600
  int*   i01      = (int*)(ws + 10240000);   // 2*1600*8
  int*   i10      = (int*)(ws + 10265600);
  float* h01p     = ws + 10291200;           // 2*1600*4*32
  float* h10p     = ws + 10700800;
  float* score_ws = ws + 11110400;           // 2*6400
  int*   jbest_ws = (int*)(ws + 11123200);
  int*   ibest_ws = (int*)(ws + 11136000);   // end: 11,148,800 floats (~44.6MB)

  float* o_h01   = out;
  float* o_h10   = out + 409600;
  float* o_score = out + 819200;
  float* o_jbest = out + 832000;
  float* o_mask  = out + 844800;
  float* o_x08   = out + 857600;
  float* o_x18   = out + 4134400;

  k_sim<<<dim3(25, 25, 2), 128, 0, stream>>>(p0, p1, sim, simT);
  k_topk<<<1600, 256, 0, stream>>>(sim, simT, i01, i10);
  k_heat<<<6400, 256, 0, stream>>>(x0, a01, h01p, x1, a10, h10p);
  k_fuse<<<3200, 256, 0, stream>>>(h01p, h10p, i01, i10, o_h01, o_h10,
                                   score_ws, jbest_ws, o_jbest, ibest_ws);
  k_final<<<50, 256, 0, stream>>>(score_ws, jbest_ws, ibest_ws, o_score, o_mask);
  k_unpatch<<<dim3(3, 80, 32), 256, 0, stream>>>(x0, o_x08, x1, o_x18);
}